// Round 2
// baseline (19665.654 us; speedup 1.0000x reference)
//
#include <hip/hip_runtime.h>
#include <hip/hip_bf16.h>

constexpr int HD = 1024;     // hidden
constexpr int VD = 50257;    // vocab
constexpr int TD = 256;      // steps

typedef __attribute__((ext_vector_type(4))) float f32x4;
typedef __attribute__((ext_vector_type(8))) short s16x8;

// workspace layout
constexpr size_t OFF_FLAGS = 0;                                   // 16 flags, stride 32 ints (128B apart)
constexpr size_t OFF_HF32  = 4096;                                // 256*1024*4 = 1 MB
constexpr size_t OFF_HBF16 = OFF_HF32 + (size_t)TD * HD * 4;      // [128][256][8] bf16 = 512 KB
constexpr size_t OFF_WHYBF = 2ull * 1024ull * 1024ull;            // 50257*1024*2 = 102.9 MB
constexpr size_t WS_NEED   = OFF_WHYBF + (size_t)VD * HD * 2;

__device__ __forceinline__ unsigned short f2bf(float f) {
    unsigned int u = __float_as_uint(f);
    u = (u + 0x7fffu + ((u >> 16) & 1u)) >> 16;   // RNE
    return (unsigned short)u;
}

// ---------------------------------------------------------------------------
// Kernel 1: sequential RNN over T steps.
// Active WGs: bid % 8 == 0 (16 of 128). Each active WG owns 64 rows of Whh,
// staged in LDS as bf16 (stride 1040 bf16 -> <=2-way bank aliasing on reads).
// Idle WGs convert Why f32 -> bf16 (overlapped with the serial RNN).
// Cross-WG handoff: per-WG flag = #steps completed (signed int; 0xAA poison
// is negative, so spinning on (flag < t) is safe without initialization).
// ---------------------------------------------------------------------------
__global__ __launch_bounds__(1024)
void rnn_seq(const int* __restrict__ chars, const float* __restrict__ Wxh,
             const float* __restrict__ Whh, const float* __restrict__ bh,
             const float* __restrict__ h0,  const float* __restrict__ Why,
             float* __restrict__ Hf32, unsigned short* __restrict__ Hbf16,
             unsigned short* __restrict__ WhyBf, int* __restrict__ flags,
             int doConvert)
{
    const int bid = blockIdx.x;
    const int tid = threadIdx.x;

    if ((bid & 7) != 0) {
        // ---- idle WG: optional Why f32 -> bf16 conversion ----
        if (doConvert) {
            const int idleIdx = bid - 1 - (bid >> 3);                 // 0..111
            const size_t total4 = (size_t)VD * HD / 4;                // float4 count
            const size_t stride = 112u * 1024u;
            const float4* src = (const float4*)Why;
            for (size_t i = (size_t)idleIdx * 1024u + tid; i < total4; i += stride) {
                float4 v = src[i];
                ushort4 o;
                o.x = f2bf(v.x); o.y = f2bf(v.y); o.z = f2bf(v.z); o.w = f2bf(v.w);
                *(ushort4*)(WhyBf + i * 4) = o;
            }
        }
        return;
    }

    // ---- active WG ----
    const int widx    = bid >> 3;          // 0..15
    const int rowbase = widx * 64;

    constexpr int WSTR = 1040;             // bf16 elements per LDS row (520 dwords, %32==8)
    __shared__ __align__(16) unsigned short Wl[64 * WSTR];   // 133,120 B
    __shared__ __align__(16) float hl[HD];                   // 4 KB

    // preload Whh rows (f32 -> bf16) into LDS
    for (int i = 0; i < 16; ++i) {
        int idx = tid + i * 1024;          // float4 index among 64*256
        int r   = idx >> 8;
        int c4  = idx & 255;
        const float4 wv = *(const float4*)(Whh + (size_t)(rowbase + r) * HD + c4 * 4);
        uint2 packed;
        packed.x = (unsigned int)f2bf(wv.x) | ((unsigned int)f2bf(wv.y) << 16);
        packed.y = (unsigned int)f2bf(wv.z) | ((unsigned int)f2bf(wv.w) << 16);
        *(uint2*)&Wl[r * WSTR + c4 * 4] = packed;
    }

    const int lane   = tid & 63;
    const int w      = tid >> 6;           // wave 0..15
    const int g      = lane >> 4;          // 0..3
    const int m      = lane & 15;          // 0..15 (k-segment within row)
    const int rlocal = w * 4 + g;          // 0..63
    const int row    = rowbase + rlocal;
    const unsigned short* wrow = &Wl[rlocal * WSTR];

    const float bhv = bh[row];
    float xv = 0.f;
    if (m == 0) xv = Wxh[(size_t)row * VD + chars[0]];   // prefetch char-0 column

    __syncthreads();   // Wl ready

    for (int t = 0; t < TD; ++t) {
        // ---- obtain h^{(t)} into LDS ----
        if (t == 0) {
            hl[tid] = h0[tid];
        } else {
            // whole wave blocks until lanes<16 see all 16 producer flags >= t
            if (lane < 16) {
                while (__hip_atomic_load(flags + lane * 32, __ATOMIC_ACQUIRE,
                                         __HIP_MEMORY_SCOPE_AGENT) < t) { }
            }
            hl[tid] = Hf32[(size_t)(t - 1) * HD + tid];
        }
        __syncthreads();

        // ---- dot: 64 k-values per lane, bf16 pairs ----
        float acc = 0.f;
        #pragma unroll 8
        for (int i = 0; i < 32; ++i) {
            const int k = 2 * m + 32 * i;
            const unsigned int wp = *(const unsigned int*)(wrow + k);
            const float2 hp = *(const float2*)(hl + k);
            acc = fmaf(__uint_as_float((wp & 0xffffu) << 16), hp.x, acc);
            acc = fmaf(__uint_as_float((wp >> 16) << 16),     hp.y, acc);
        }
        // reduce across 16 lanes of the row group
        acc += __shfl_xor(acc, 1);
        acc += __shfl_xor(acc, 2);
        acc += __shfl_xor(acc, 4);
        acc += __shfl_xor(acc, 8);

        if (m == 0) {
            const float hn = tanhf(acc + bhv + xv);
            Hf32[(size_t)t * HD + row] = hn;
            // GEMM B layout: [k>>3][t][k&7]
            Hbf16[((size_t)(row >> 3) * TD + t) * 8 + (row & 7)] = f2bf(hn);
        }
        // prefetch next step's Wxh column (hides the gather latency)
        if (m == 0 && t + 1 < TD) xv = Wxh[(size_t)row * VD + chars[t + 1]];

        __threadfence();       // make this WG's h-chunk agent-visible
        __syncthreads();
        if (tid == 0) {
            __hip_atomic_store(flags + widx * 32, t + 1, __ATOMIC_RELEASE,
                               __HIP_MEMORY_SCOPE_AGENT);
        }
    }
}

// ---------------------------------------------------------------------------
// Kernel 2: logits = Why @ H + by  -> d_out[t*V + v]   (m97-style bf16 MFMA)
// Block: 256 thr (4 waves), BM=64 rows, BN=256 (all T), BK=32, 32 k-iters.
// A and B both stored K-contiguous (same structure as the verified gemm_bt).
// ---------------------------------------------------------------------------
__global__ __launch_bounds__(256)
void gemm_logits(const float* __restrict__ Why, const unsigned short* __restrict__ WhyBf,
                 const unsigned short* __restrict__ Hbf16, const float* __restrict__ by,
                 float* __restrict__ out, int useBf)
{
    constexpr int ASTR = 40;                                  // bf16 elems/row (pad vs 32)
    __shared__ __align__(16) unsigned short Al[64 * ASTR];    // 5,120 B
    __shared__ __align__(16) unsigned short Bl[4 * 256 * 8];  // 16,384 B

    const int tid   = threadIdx.x;
    const int bid   = blockIdx.x;
    const int vbase = bid * 64;
    const int lane  = tid & 63;
    const int w     = tid >> 6;      // 0..3 : 16-row slice
    const int m     = lane & 15;
    const int g     = lane >> 4;

    f32x4 acc[16];
    #pragma unroll
    for (int n = 0; n < 16; ++n) acc[n] = (f32x4){0.f, 0.f, 0.f, 0.f};

    for (int kb = 0; kb < 32; ++kb) {
        const int kbase = kb * 32;
        // stage A (64 rows x 32 k, bf16)
        if (useBf) {
            const int r = tid >> 2, q = tid & 3;              // 64 rows x 4 chunks
            int rowi = vbase + r; if (rowi >= VD) rowi = VD - 1;
            const uint4 av = *(const uint4*)(WhyBf + (size_t)rowi * HD + kbase + q * 8);
            *(uint4*)&Al[r * ASTR + q * 8] = av;
        } else {
            // f32 path: 256 threads x 2 float4 = 512 float4 = all 64 rows
            const int r = tid >> 3, q = tid & 7;              // 32 rows x 8 chunks
            #pragma unroll
            for (int hrow = 0; hrow < 2; ++hrow) {
                const int rr = r + hrow * 32;
                int rowi = vbase + rr; if (rowi >= VD) rowi = VD - 1;
                const float4 av = *(const float4*)(Why + (size_t)rowi * HD + kbase + q * 4);
                uint2 packed;
                packed.x = (unsigned int)f2bf(av.x) | ((unsigned int)f2bf(av.y) << 16);
                packed.y = (unsigned int)f2bf(av.z) | ((unsigned int)f2bf(av.w) << 16);
                *(uint2*)&Al[rr * ASTR + q * 4] = packed;
            }
        }
        // stage B: contiguous 16 KB chunk of Hbf16 ([kb*4 .. kb*4+4)[t][8])
        {
            const uint4* src = (const uint4*)(Hbf16 + (size_t)kb * 8192);
            uint4* dst = (uint4*)Bl;
            #pragma unroll
            for (int i = 0; i < 4; ++i) dst[tid + i * 256] = src[tid + i * 256];
        }
        __syncthreads();

        const s16x8 af = *(const s16x8*)&Al[(w * 16 + m) * ASTR + g * 8];
        #pragma unroll
        for (int n = 0; n < 16; ++n) {
            const s16x8 bf = *(const s16x8*)&Bl[((size_t)g * 256 + n * 16 + m) * 8];
            acc[n] = __builtin_amdgcn_mfma_f32_16x16x32_bf16(af, bf, acc[n], 0, 0, 0);
        }
        __syncthreads();
    }

    // epilogue: D row = v = vbase + w*16 + g*4 + r ; D col = t = n*16 + m
    const int row0 = vbase + w * 16 + g * 4;
    float byv[4];
    #pragma unroll
    for (int r = 0; r < 4; ++r) byv[r] = (row0 + r < VD) ? by[row0 + r] : 0.f;

    #pragma unroll
    for (int n = 0; n < 16; ++n) {
        const int t = n * 16 + m;
        float* o = out + (size_t)t * VD + row0;
        #pragma unroll
        for (int r = 0; r < 4; ++r) {
            if (row0 + r < VD) o[r] = acc[n][r] + byv[r];
        }
    }
}

// ---------------------------------------------------------------------------
// Kernel 3: in-place softmax over V for each t. One 1024-thr WG per t.
// Logits kept in 50 registers (fully unrolled -> static indexing, no scratch).
// ---------------------------------------------------------------------------
__global__ __launch_bounds__(1024)
void softmax_rows(float* __restrict__ out)
{
    const int t   = blockIdx.x;
    const int tid = threadIdx.x;
    float* row = out + (size_t)t * VD;

    float vals[50];
    float mx = -3.4e38f;
    #pragma unroll
    for (int i = 0; i < 50; ++i) {
        const int v = i * 1024 + tid;
        vals[i] = (v < VD) ? row[v] : -3.4e38f;
        mx = fmaxf(mx, vals[i]);
    }
    #pragma unroll
    for (int s = 1; s < 64; s <<= 1) mx = fmaxf(mx, __shfl_xor(mx, s));

    __shared__ float redm[16];
    __shared__ float reds[16];
    const int w = tid >> 6, lane = tid & 63;
    if (lane == 0) redm[w] = mx;
    __syncthreads();
    if (w == 0) {
        float v = (lane < 16) ? redm[lane] : -3.4e38f;
        #pragma unroll
        for (int s = 1; s < 16; s <<= 1) v = fmaxf(v, __shfl_xor(v, s));
        if (lane == 0) redm[0] = v;
    }
    __syncthreads();
    mx = redm[0];

    float sum = 0.f;
    #pragma unroll
    for (int i = 0; i < 50; ++i) {
        const int v = i * 1024 + tid;
        const float e = (v < VD) ? expf(vals[i] - mx) : 0.f;
        vals[i] = e;
        sum += e;
    }
    #pragma unroll
    for (int s = 1; s < 64; s <<= 1) sum += __shfl_xor(sum, s);
    if (lane == 0) reds[w] = sum;
    __syncthreads();
    if (w == 0) {
        float v = (lane < 16) ? reds[lane] : 0.f;
        #pragma unroll
        for (int s = 1; s < 16; s <<= 1) v += __shfl_xor(v, s);
        if (lane == 0) reds[0] = v;
    }
    __syncthreads();
    const float inv = 1.0f / reds[0];

    #pragma unroll
    for (int i = 0; i < 50; ++i) {
        const int v = i * 1024 + tid;
        if (v < VD) row[v] = vals[i] * inv;
    }
}

// ---------------------------------------------------------------------------
extern "C" void kernel_launch(void* const* d_in, const int* in_sizes, int n_in,
                              void* d_out, int out_size, void* d_ws, size_t ws_size,
                              hipStream_t stream)
{
    const int*   chars = (const int*)  d_in[0];
    const float* Wxh   = (const float*)d_in[1];
    const float* Whh   = (const float*)d_in[2];
    const float* Why   = (const float*)d_in[3];
    const float* bh    = (const float*)d_in[4];
    const float* by    = (const float*)d_in[5];
    const float* h0    = (const float*)d_in[6];

    char* ws = (char*)d_ws;
    int*            flags = (int*)           (ws + OFF_FLAGS);
    float*          Hf32  = (float*)         (ws + OFF_HF32);
    unsigned short* Hbf16 = (unsigned short*)(ws + OFF_HBF16);
    unsigned short* WhyBf = (unsigned short*)(ws + OFF_WHYBF);
    const int doConvert = (ws_size >= WS_NEED) ? 1 : 0;

    rnn_seq<<<128, 1024, 0, stream>>>(chars, Wxh, Whh, bh, h0, Why,
                                      Hf32, Hbf16, WhyBf, flags, doConvert);

    const int gemmBlocks = (VD + 63) / 64;   // 786
    gemm_logits<<<gemmBlocks, 256, 0, stream>>>(Why, WhyBf, Hbf16, by,
                                                (float*)d_out, doConvert);

    softmax_rows<<<TD, 1024, 0, stream>>>((float*)d_out);
}

// Round 3
// 1243.722 us; speedup vs baseline: 15.8119x; 15.8119x over previous
//
#include <hip/hip_runtime.h>
#include <hip/hip_bf16.h>

constexpr int HD = 1024;     // hidden
constexpr int VD = 50257;    // vocab
constexpr int TD = 256;      // steps

typedef __attribute__((ext_vector_type(4))) float f32x4;
typedef __attribute__((ext_vector_type(8))) short s16x8;

// workspace layout
constexpr size_t OFF_HTAG  = 4096;                                // [T][H] uint64 (tag<<32 | f32 bits) = 2 MB
constexpr size_t OFF_HBF16 = 3ull * 1024 * 1024;                  // [128][256][8] bf16 = 512 KB
constexpr size_t OFF_WHYBF = 4ull * 1024 * 1024;                  // 50257*1024*2 = 102.9 MB
constexpr size_t WS_NEED   = OFF_WHYBF + (size_t)VD * HD * 2;

__device__ __forceinline__ unsigned short f2bf(float f) {
    unsigned int u = __float_as_uint(f);
    u = (u + 0x7fffu + ((u >> 16) & 1u)) >> 16;   // RNE
    return (unsigned short)u;
}

// ---------------------------------------------------------------------------
// Kernel 1: sequential RNN over T steps.
// Active WGs: bid % 8 == 0 (16 of 128). Each active WG owns 64 rows of Whh,
// staged in LDS as bf16 (stride 1040 bf16 -> <=2-way bank aliasing on reads).
// Idle WGs convert Why f32 -> bf16 (overlapped with the serial RNN).
//
// Cross-WG handoff: NO fences, NO acquire/release (those emit per-XCD L2
// invalidate/writeback on gfx950 -> 75 us/step fence storm, R2 counters).
// Instead each h element is published as a 64-bit RELAXED agent-scope atomic
// word (tag<<32 | f32 bits), tag = t+1. Relaxed agent atomics are plain
// sc0/sc1 memory ops to the coherence point -- no cache maintenance. Word
// atomicity makes the data self-validating; 0xAA ws poison never matches a
// valid tag (1..256).
// ---------------------------------------------------------------------------
__global__ __launch_bounds__(1024)
void rnn_seq(const int* __restrict__ chars, const float* __restrict__ Wxh,
             const float* __restrict__ Whh, const float* __restrict__ bh,
             const float* __restrict__ h0,  const float* __restrict__ Why,
             unsigned long long* __restrict__ Htag,
             unsigned short* __restrict__ Hbf16,
             unsigned short* __restrict__ WhyBf,
             int doConvert)
{
    const int bid = blockIdx.x;
    const int tid = threadIdx.x;

    if ((bid & 7) != 0) {
        // ---- idle WG: Why f32 -> bf16 conversion (overlapped, off critical path)
        if (doConvert) {
            const int idleIdx = bid - 1 - (bid >> 3);                 // 0..111
            const size_t total4 = (size_t)VD * HD / 4;                // float4 count
            const size_t stride = 112u * 1024u;
            const float4* src = (const float4*)Why;
            for (size_t i = (size_t)idleIdx * 1024u + tid; i < total4; i += stride) {
                float4 v = src[i];
                ushort4 o;
                o.x = f2bf(v.x); o.y = f2bf(v.y); o.z = f2bf(v.z); o.w = f2bf(v.w);
                *(ushort4*)(WhyBf + i * 4) = o;
            }
        }
        return;
    }

    // ---- active WG ----
    const int widx    = bid >> 3;          // 0..15
    const int rowbase = widx * 64;

    constexpr int WSTR = 1040;             // bf16 elements per LDS row
    __shared__ __align__(16) unsigned short Wl[64 * WSTR];   // 133,120 B
    __shared__ __align__(16) float hl[HD];                   // 4 KB

    // preload Whh rows (f32 -> bf16) into LDS
    for (int i = 0; i < 16; ++i) {
        int idx = tid + i * 1024;          // float4 index among 64*256
        int r   = idx >> 8;
        int c4  = idx & 255;
        const float4 wv = *(const float4*)(Whh + (size_t)(rowbase + r) * HD + c4 * 4);
        uint2 packed;
        packed.x = (unsigned int)f2bf(wv.x) | ((unsigned int)f2bf(wv.y) << 16);
        packed.y = (unsigned int)f2bf(wv.z) | ((unsigned int)f2bf(wv.w) << 16);
        *(uint2*)&Wl[r * WSTR + c4 * 4] = packed;
    }

    const int lane   = tid & 63;
    const int w      = tid >> 6;           // wave 0..15
    const int g      = lane >> 4;          // 0..3
    const int m      = lane & 15;          // 0..15 (k-segment within row)
    const int rlocal = w * 4 + g;          // 0..63
    const int row    = rowbase + rlocal;
    const unsigned short* wrow = &Wl[rlocal * WSTR];

    const float bhv = bh[row];
    float xv = 0.f;
    if (m == 0) xv = Wxh[(size_t)row * VD + chars[0]];   // prefetch char-0 column

    __syncthreads();   // Wl ready

    for (int t = 0; t < TD; ++t) {
        // ---- obtain h^{(t)} into LDS ----
        if (t == 0) {
            hl[tid] = h0[tid];
        } else {
            // spin on OWN element's tag (relaxed, agent scope -> no cache ops)
            const unsigned long long want = (unsigned long long)t;   // producer wrote (t-1)+1
            unsigned long long v;
            do {
                v = __hip_atomic_load(Htag + (size_t)(t - 1) * HD + tid,
                                      __ATOMIC_RELAXED, __HIP_MEMORY_SCOPE_AGENT);
            } while ((v >> 32) != want);
            hl[tid] = __uint_as_float((unsigned int)v);
        }
        __syncthreads();

        // ---- dot: 64 k-values per lane, bf16 pairs ----
        float acc = 0.f;
        #pragma unroll 8
        for (int i = 0; i < 32; ++i) {
            const int k = 2 * m + 32 * i;
            const unsigned int wp = *(const unsigned int*)(wrow + k);
            const float2 hp = *(const float2*)(hl + k);
            acc = fmaf(__uint_as_float(wp << 16),          hp.x, acc);
            acc = fmaf(__uint_as_float(wp & 0xffff0000u),  hp.y, acc);
        }
        // reduce across 16 lanes of the row group
        acc += __shfl_xor(acc, 1);
        acc += __shfl_xor(acc, 2);
        acc += __shfl_xor(acc, 4);
        acc += __shfl_xor(acc, 8);

        if (m == 0) {
            const float hn = tanhf(acc + bhv + xv);
            // publish immediately: tagged 64-bit relaxed store (data IS the flag)
            __hip_atomic_store(Htag + (size_t)t * HD + row,
                               ((unsigned long long)(t + 1) << 32) |
                               (unsigned long long)__float_as_uint(hn),
                               __ATOMIC_RELAXED, __HIP_MEMORY_SCOPE_AGENT);
            // GEMM B layout: [k>>3][t][k&7]
            Hbf16[((size_t)(row >> 3) * TD + t) * 8 + (row & 7)] = f2bf(hn);
        }
        // prefetch next step's Wxh column (hides the gather latency)
        if (m == 0 && t + 1 < TD) xv = Wxh[(size_t)row * VD + chars[t + 1]];

        __syncthreads();   // all waves done reading hl before next overwrite
    }
}

// ---------------------------------------------------------------------------
// Kernel 2: logits = Why @ H + by  -> d_out[t*V + v]   (m97-style bf16 MFMA)
// Block: 256 thr (4 waves), BM=64 rows, BN=256 (all T), BK=32, 32 k-iters.
// ---------------------------------------------------------------------------
__global__ __launch_bounds__(256)
void gemm_logits(const float* __restrict__ Why, const unsigned short* __restrict__ WhyBf,
                 const unsigned short* __restrict__ Hbf16, const float* __restrict__ by,
                 float* __restrict__ out, int useBf)
{
    constexpr int ASTR = 40;                                  // bf16 elems/row (pad vs 32)
    __shared__ __align__(16) unsigned short Al[64 * ASTR];    // 5,120 B
    __shared__ __align__(16) unsigned short Bl[4 * 256 * 8];  // 16,384 B

    const int tid   = threadIdx.x;
    const int bid   = blockIdx.x;
    const int vbase = bid * 64;
    const int lane  = tid & 63;
    const int w     = tid >> 6;      // 0..3 : 16-row slice
    const int m     = lane & 15;
    const int g     = lane >> 4;

    f32x4 acc[16];
    #pragma unroll
    for (int n = 0; n < 16; ++n) acc[n] = (f32x4){0.f, 0.f, 0.f, 0.f};

    for (int kb = 0; kb < 32; ++kb) {
        const int kbase = kb * 32;
        // stage A (64 rows x 32 k, bf16)
        if (useBf) {
            const int r = tid >> 2, q = tid & 3;              // 64 rows x 4 chunks
            int rowi = vbase + r; if (rowi >= VD) rowi = VD - 1;
            const uint4 av = *(const uint4*)(WhyBf + (size_t)rowi * HD + kbase + q * 8);
            *(uint4*)&Al[r * ASTR + q * 8] = av;
        } else {
            // f32 path: 256 threads x 2 float4 = all 64 rows
            const int r = tid >> 3, q = tid & 7;
            #pragma unroll
            for (int hrow = 0; hrow < 2; ++hrow) {
                const int rr = r + hrow * 32;
                int rowi = vbase + rr; if (rowi >= VD) rowi = VD - 1;
                const float4 av = *(const float4*)(Why + (size_t)rowi * HD + kbase + q * 4);
                uint2 packed;
                packed.x = (unsigned int)f2bf(av.x) | ((unsigned int)f2bf(av.y) << 16);
                packed.y = (unsigned int)f2bf(av.z) | ((unsigned int)f2bf(av.w) << 16);
                *(uint2*)&Al[rr * ASTR + q * 4] = packed;
            }
        }
        // stage B: contiguous 16 KB chunk of Hbf16 ([kb*4 .. kb*4+4)[t][8])
        {
            const uint4* src = (const uint4*)(Hbf16 + (size_t)kb * 8192);
            uint4* dst = (uint4*)Bl;
            #pragma unroll
            for (int i = 0; i < 4; ++i) dst[tid + i * 256] = src[tid + i * 256];
        }
        __syncthreads();

        const s16x8 af = *(const s16x8*)&Al[(w * 16 + m) * ASTR + g * 8];
        #pragma unroll
        for (int n = 0; n < 16; ++n) {
            const s16x8 bf = *(const s16x8*)&Bl[((size_t)g * 256 + n * 16 + m) * 8];
            acc[n] = __builtin_amdgcn_mfma_f32_16x16x32_bf16(af, bf, acc[n], 0, 0, 0);
        }
        __syncthreads();
    }

    // epilogue: D row = v = vbase + w*16 + g*4 + r ; D col = t = n*16 + m
    const int row0 = vbase + w * 16 + g * 4;
    float byv[4];
    #pragma unroll
    for (int r = 0; r < 4; ++r) byv[r] = (row0 + r < VD) ? by[row0 + r] : 0.f;

    #pragma unroll
    for (int n = 0; n < 16; ++n) {
        const int t = n * 16 + m;
        float* o = out + (size_t)t * VD + row0;
        #pragma unroll
        for (int r = 0; r < 4; ++r) {
            if (row0 + r < VD) o[r] = acc[n][r] + byv[r];
        }
    }
}

// ---------------------------------------------------------------------------
// Kernel 3: in-place softmax over V for each t. One 1024-thr WG per t.
// ---------------------------------------------------------------------------
__global__ __launch_bounds__(1024)
void softmax_rows(float* __restrict__ out)
{
    const int t   = blockIdx.x;
    const int tid = threadIdx.x;
    float* row = out + (size_t)t * VD;

    float vals[50];
    float mx = -3.4e38f;
    #pragma unroll
    for (int i = 0; i < 50; ++i) {
        const int v = i * 1024 + tid;
        vals[i] = (v < VD) ? row[v] : -3.4e38f;
        mx = fmaxf(mx, vals[i]);
    }
    #pragma unroll
    for (int s = 1; s < 64; s <<= 1) mx = fmaxf(mx, __shfl_xor(mx, s));

    __shared__ float redm[16];
    __shared__ float reds[16];
    const int w = tid >> 6, lane = tid & 63;
    if (lane == 0) redm[w] = mx;
    __syncthreads();
    if (w == 0) {
        float v = (lane < 16) ? redm[lane] : -3.4e38f;
        #pragma unroll
        for (int s = 1; s < 16; s <<= 1) v = fmaxf(v, __shfl_xor(v, s));
        if (lane == 0) redm[0] = v;
    }
    __syncthreads();
    mx = redm[0];

    float sum = 0.f;
    #pragma unroll
    for (int i = 0; i < 50; ++i) {
        const int v = i * 1024 + tid;
        const float e = (v < VD) ? expf(vals[i] - mx) : 0.f;
        vals[i] = e;
        sum += e;
    }
    #pragma unroll
    for (int s = 1; s < 64; s <<= 1) sum += __shfl_xor(sum, s);
    if (lane == 0) reds[w] = sum;
    __syncthreads();
    if (w == 0) {
        float v = (lane < 16) ? reds[lane] : 0.f;
        #pragma unroll
        for (int s = 1; s < 16; s <<= 1) v += __shfl_xor(v, s);
        if (lane == 0) reds[0] = v;
    }
    __syncthreads();
    const float inv = 1.0f / reds[0];

    #pragma unroll
    for (int i = 0; i < 50; ++i) {
        const int v = i * 1024 + tid;
        if (v < VD) row[v] = vals[i] * inv;
    }
}

// ---------------------------------------------------------------------------
extern "C" void kernel_launch(void* const* d_in, const int* in_sizes, int n_in,
                              void* d_out, int out_size, void* d_ws, size_t ws_size,
                              hipStream_t stream)
{
    const int*   chars = (const int*)  d_in[0];
    const float* Wxh   = (const float*)d_in[1];
    const float* Whh   = (const float*)d_in[2];
    const float* Why   = (const float*)d_in[3];
    const float* bh    = (const float*)d_in[4];
    const float* by    = (const float*)d_in[5];
    const float* h0    = (const float*)d_in[6];

    char* ws = (char*)d_ws;
    unsigned long long* Htag  = (unsigned long long*)(ws + OFF_HTAG);
    unsigned short*     Hbf16 = (unsigned short*)    (ws + OFF_HBF16);
    unsigned short*     WhyBf = (unsigned short*)    (ws + OFF_WHYBF);
    const int doConvert = (ws_size >= WS_NEED) ? 1 : 0;

    rnn_seq<<<128, 1024, 0, stream>>>(chars, Wxh, Whh, bh, h0, Why,
                                      Htag, Hbf16, WhyBf, doConvert);

    const int gemmBlocks = (VD + 63) / 64;   // 786
    gemm_logits<<<gemmBlocks, 256, 0, stream>>>(Why, WhyBf, Hbf16, by,
                                                (float*)d_out, doConvert);

    softmax_rows<<<TD, 1024, 0, stream>>>((float*)d_out);
}